// Round 5
// baseline (142.498 us; speedup 1.0000x reference)
//
#include <hip/hip_runtime.h>

typedef unsigned short u16;
typedef short bf16x8 __attribute__((ext_vector_type(8)));
typedef float f32x4 __attribute__((ext_vector_type(4)));
typedef u16 u16x4 __attribute__((ext_vector_type(4)));

__device__ __forceinline__ float b2f(u16 h) {
  unsigned u = ((unsigned)h) << 16;
  return __builtin_bit_cast(float, u);
}
__device__ __forceinline__ u16 f2b(float f) {
  unsigned u = __builtin_bit_cast(unsigned, f);
  u = u + 0x7fffu + ((u >> 16) & 1u);   // round-to-nearest-even
  return (u16)(u >> 16);
}

#if defined(__has_builtin)
#if __has_builtin(__builtin_amdgcn_cvt_pk_bf16_f32)
#define HAVE_CVT_PK_BF16 1
#endif
#endif

__device__ __forceinline__ unsigned f2b_pk(float a, float b) {
#ifdef HAVE_CVT_PK_BF16
  auto v = __builtin_amdgcn_cvt_pk_bf16_f32(a, b);   // D.lo=cvt(a), D.hi=cvt(b)
  unsigned r;
  __builtin_memcpy(&r, &v, 4);
  return r;
#else
  return (unsigned)f2b(a) | (((unsigned)f2b(b)) << 16);
#endif
}
__device__ __forceinline__ bf16x8 pack8(const float* v) {
  union { unsigned u[4]; bf16x8 o; } r;
  r.u[0] = f2b_pk(v[0], v[1]);
  r.u[1] = f2b_pk(v[2], v[3]);
  r.u[2] = f2b_pk(v[4], v[5]);
  r.u[3] = f2b_pk(v[6], v[7]);
  return r.o;
}
__device__ __forceinline__ u16x4 pack4(float a, float b, float c, float d) {
  union { unsigned u[2]; u16x4 o; } r;
  r.u[0] = f2b_pk(a, b);
  r.u[1] = f2b_pk(c, d);
  return r.o;
}

// ---------------------------------------------------------------------------
// K1: blocks [0,128)  : pre-chain GEMM for 16 nodes each (reads x + pre_w
//                       fp32 directly, converts in-register) -> flat bf16
//     blocks [128,192): post_w fp32 -> bf16 STAGED layout [s8(32)][m(256)][8]
// ---------------------------------------------------------------------------
__global__ __launch_bounds__(256, 2) void dense_edge_k1(
    const float* __restrict__ x, const float* __restrict__ pre_w,
    const float* __restrict__ preb, const float* __restrict__ post_w,
    u16* __restrict__ wpost, u16* __restrict__ flat) {
  const int blk = blockIdx.x;
  const int t = threadIdx.x;
  if (blk >= 128) {
    // ---- post-weight staging ----
    const int id = (blk - 128) * 256 + t;   // 16384 slots of 8 elems
    const int layer = id >> 13;             // 0..1
    const int sid = id & 8191;
    const int m = sid >> 5;
    const int s8 = sid & 31;
    const float* src = post_w + layer * 65536 + m * 256 + s8 * 8;
    f32x4 a = *(const f32x4*)(src);
    f32x4 c = *(const f32x4*)(src + 4);
    float tmp[8] = {a[0], a[1], a[2], a[3], c[0], c[1], c[2], c[3]};
    *(bf16x8*)(wpost + layer * 65536 + (s8 * 256 + m) * 8) = pack8(tmp);
    return;
  }
  // ---- pre-chain for nodes [blk*16, blk*16+16) ----
  __shared__ float xtile[256 * 20];  // [c][n] fp32, pad 20 for banks (20 KB)
  __shared__ u16 feat[2][4096];      // [32 s8][16 n][8] bf16 ping-pong
  const int wv = t >> 6, ln = t & 63;
  const int q4 = ln >> 4, r15 = ln & 15;
  const int nb = blk * 16;
  const int b = nb >> 10;
  const int hw0 = nb & 1023;

  {  // load this block's x slice: thread t = channel, 16 nodes
    const float* src = x + (b * 256 + t) * 1024 + hw0;
    f32x4 v0 = *(const f32x4*)(src);
    f32x4 v1 = *(const f32x4*)(src + 4);
    f32x4 v2 = *(const f32x4*)(src + 8);
    f32x4 v3 = *(const f32x4*)(src + 12);
    *(f32x4*)&xtile[t * 20 + 0] = v0;
    *(f32x4*)&xtile[t * 20 + 4] = v1;
    *(f32x4*)&xtile[t * 20 + 8] = v2;
    *(f32x4*)&xtile[t * 20 + 12] = v3;
  }
  __syncthreads();
  // feat[0] = bf16 transpose [s8][n][8]
#pragma unroll
  for (int rep = 0; rep < 2; rep++) {
    const int id = rep * 256 + t;
    const int n = id & 15, s8 = id >> 4;
    float tmp[8];
#pragma unroll
    for (int j = 0; j < 8; j++) tmp[j] = xtile[(s8 * 8 + j) * 20 + n];
    *(bf16x8*)(&feat[0][(s8 * 16 + n) * 8]) = pack8(tmp);
  }
  __syncthreads();

#pragma unroll
  for (int l = 0; l < 3; l++) {
    const float* wl = pre_w + l * 65536;
    f32x4 acc[4];
    f32x4 zero = {0.f, 0.f, 0.f, 0.f};
#pragma unroll
    for (int mt = 0; mt < 4; mt++) acc[mt] = zero;
#pragma unroll
    for (int s = 0; s < 8; s++) {
      bf16x8 bv = *(const bf16x8*)(&feat[l & 1][((s * 4 + q4) * 16 + r15) * 8]);
#pragma unroll
      for (int mt = 0; mt < 4; mt++) {
        const float* wp = wl + (wv * 64 + mt * 16 + r15) * 256 + (s * 4 + q4) * 8;
        f32x4 wa = *(const f32x4*)(wp);
        f32x4 wc = *(const f32x4*)(wp + 4);
        float tmp[8] = {wa[0], wa[1], wa[2], wa[3], wc[0], wc[1], wc[2], wc[3]};
        bf16x8 av = pack8(tmp);
        acc[mt] = __builtin_amdgcn_mfma_f32_16x16x32_bf16(av, bv, acc[mt], 0, 0, 0);
      }
    }
    if (l < 2) {
#pragma unroll
      for (int mt = 0; mt < 4; mt++) {
        const int o = wv * 64 + mt * 16 + q4 * 4;
        f32x4 bb = *(const f32x4*)(preb + l * 256 + o);
        float v0 = fmaxf(acc[mt][0] + bb[0], 0.f);
        float v1 = fmaxf(acc[mt][1] + bb[1], 0.f);
        float v2 = fmaxf(acc[mt][2] + bb[2], 0.f);
        float v3 = fmaxf(acc[mt][3] + bb[3], 0.f);
        *(u16x4*)(&feat[(l + 1) & 1][((o >> 3) * 16 + r15) * 8 + (o & 7)]) =
            pack4(v0, v1, v2, v3);
      }
      __syncthreads();
    } else {
#pragma unroll
      for (int mt = 0; mt < 4; mt++) {
        const int o = wv * 64 + mt * 16 + q4 * 4;
        f32x4 bb = *(const f32x4*)(preb + 512 + o);
        *(u16x4*)(flat + (nb + r15) * 256 + o) =
            pack4(acc[mt][0] + bb[0], acc[mt][1] + bb[1],
                  acc[mt][2] + bb[2], acc[mt][3] + bb[3]);   // no relu
      }
    }
  }
}

// ---------------------------------------------------------------------------
// main: fused GEMM1+GEMM2+W3, wave-specialized, 1024 threads = 16 waves.
// Waves 0-7 (producers): W1 rows [wv*32, wv*32+32) in regs; build XX; GEMM1.
// Waves 8-15 (consumers): W2 rows in regs; GEMM2 + W3 epilogue + store.
// VGPR <= 128/lane -> all 16 waves resident (4/SIMD). 256 blocks x 8 tiles.
// Step j: P1 = build XX(j) || GEMM2(j-1)+partials ; barrier ;
//         P2 = GEMM1(j)->t1buf || out-store(j-1)   ; barrier.
// ---------------------------------------------------------------------------
__global__ __launch_bounds__(1024, 4) void dense_edge_main(
    const u16* __restrict__ flat, const int* __restrict__ pidx,
    const int* __restrict__ cidx, const u16* __restrict__ w1s,
    const u16* __restrict__ w2s, const float* __restrict__ b1,
    const float* __restrict__ b2, const float* __restrict__ w3,
    const float* __restrict__ b3, float* __restrict__ out) {
  __shared__ u16 xxbuf[16384];      // 32 KB [s8(32)][n(64)][8]
  __shared__ u16 t1buf[16384];      // 32 KB same layout
  __shared__ float pbuf[8][2][64];  // 4 KB consumer partials

  const int t = threadIdx.x;
  const int wv = t >> 6;            // 0..15
  const int ln = t & 63;
  const int q4 = ln >> 4, r15 = ln & 15;
  const bool prod = wv < 8;
  const int cw = wv & 7;            // role-wave id; m-rows = cw*32..cw*32+31
  const int blk = blockIdx.x;       // 256 blocks
  const int tile0 = blk * 8;
  const int b = tile0 >> 10;
  const int pt = (tile0 >> 5) & 31;
  const int qt0 = tile0 & 31;
  const int p0 = pt * 8;

  // role weights: 16 fragments = 64 VGPR (coalesced 256B rows, staged layout)
  const u16* wsrc = prod ? w1s : w2s;
  bf16x8 af_w[2][8];
#pragma unroll
  for (int s = 0; s < 8; s++)
#pragma unroll
    for (int mt = 0; mt < 2; mt++)
      af_w[mt][s] = *(const bf16x8*)(wsrc + ((s * 4 + q4) * 256 + cw * 32 + mt * 16 + r15) * 8);

  int pn = 0;
  if (prod) pn = pidx[b * 256 + p0 + (ln >> 3)];
  const u16* prow = flat + pn * 256 + cw * 32;  // L1-hot across tiles

#pragma unroll 1
  for (int j = 0; j <= 8; j++) {
    // ---------------- P1 ----------------
    if (prod) {
      if (j < 8) {
        const int qn = cidx[b * 256 + (qt0 + j) * 8 + (ln & 7)];
        const u16* qrow = flat + qn * 256 + cw * 32;
#pragma unroll
        for (int i = 0; i < 4; i++) {
          bf16x8 av = *(const bf16x8*)(prow + i * 8);
          bf16x8 bv = *(const bf16x8*)(qrow + i * 8);
          float d[8];
#pragma unroll
          for (int jj = 0; jj < 8; jj++) {
            float dv = b2f((u16)av[jj]) - b2f((u16)bv[jj]);
            d[jj] = dv * dv;
          }
          *(bf16x8*)(xxbuf + ((cw * 4 + i) * 64 + ln) * 8) = pack8(d);
        }
      }
    } else if (j > 0) {
      // GEMM2 on tile j-1 from t1buf
      f32x4 acc[2][4];
      {
        f32x4 zero = {0.f, 0.f, 0.f, 0.f};
#pragma unroll
        for (int mt = 0; mt < 2; mt++)
#pragma unroll
          for (int nt = 0; nt < 4; nt++) acc[mt][nt] = zero;
      }
#pragma unroll
      for (int s = 0; s < 8; s++) {
        bf16x8 bfr[4];
#pragma unroll
        for (int nt = 0; nt < 4; nt++)
          bfr[nt] = *(const bf16x8*)(t1buf + ((s * 4 + q4) * 64 + nt * 16 + r15) * 8);
#pragma unroll
        for (int mt = 0; mt < 2; mt++)
#pragma unroll
          for (int nt = 0; nt < 4; nt++)
            acc[mt][nt] = __builtin_amdgcn_mfma_f32_16x16x32_bf16(af_w[mt][s], bfr[nt], acc[mt][nt], 0, 0, 0);
      }
      // W3 epilogue partials over this wave's 32 rows
      float part[2][4] = {{0.f, 0.f, 0.f, 0.f}, {0.f, 0.f, 0.f, 0.f}};
#pragma unroll
      for (int mt = 0; mt < 2; mt++) {
        const int o = cw * 32 + mt * 16 + q4 * 4;
        f32x4 bb = *(const f32x4*)(b2 + o);
        f32x4 w3a = *(const f32x4*)(w3 + o);
        f32x4 w3b = *(const f32x4*)(w3 + 256 + o);
#pragma unroll
        for (int nt = 0; nt < 4; nt++) {
#pragma unroll
          for (int r = 0; r < 4; r++) {
            float v = fmaxf(acc[mt][nt][r] + bb[r], 0.f);
            part[0][nt] += v * w3a[r];
            part[1][nt] += v * w3b[r];
          }
        }
      }
#pragma unroll
      for (int o3 = 0; o3 < 2; o3++)
#pragma unroll
        for (int nt = 0; nt < 4; nt++) {
          part[o3][nt] += __shfl_xor(part[o3][nt], 16, 64);
          part[o3][nt] += __shfl_xor(part[o3][nt], 32, 64);
        }
      if (q4 == 0) {
#pragma unroll
        for (int o3 = 0; o3 < 2; o3++)
#pragma unroll
          for (int nt = 0; nt < 4; nt++)
            pbuf[cw][o3][nt * 16 + r15] = part[o3][nt];
      }
    }
    __syncthreads();

    // ---------------- P2 ----------------
    if (prod) {
      if (j < 8) {
        f32x4 acc[2][4];
        {
          f32x4 zero = {0.f, 0.f, 0.f, 0.f};
#pragma unroll
          for (int mt = 0; mt < 2; mt++)
#pragma unroll
            for (int nt = 0; nt < 4; nt++) acc[mt][nt] = zero;
        }
#pragma unroll
        for (int s = 0; s < 8; s++) {
          bf16x8 bfr[4];
#pragma unroll
          for (int nt = 0; nt < 4; nt++)
            bfr[nt] = *(const bf16x8*)(xxbuf + ((s * 4 + q4) * 64 + nt * 16 + r15) * 8);
#pragma unroll
          for (int mt = 0; mt < 2; mt++)
#pragma unroll
            for (int nt = 0; nt < 4; nt++)
              acc[mt][nt] = __builtin_amdgcn_mfma_f32_16x16x32_bf16(af_w[mt][s], bfr[nt], acc[mt][nt], 0, 0, 0);
        }
        // relu + b1 -> t1buf
#pragma unroll
        for (int mt = 0; mt < 2; mt++) {
          const int o = cw * 32 + mt * 16 + q4 * 4;
          f32x4 bb = *(const f32x4*)(b1 + o);
#pragma unroll
          for (int nt = 0; nt < 4; nt++) {
            const int nn = nt * 16 + r15;
            float v0 = fmaxf(acc[mt][nt][0] + bb[0], 0.f);
            float v1 = fmaxf(acc[mt][nt][1] + bb[1], 0.f);
            float v2 = fmaxf(acc[mt][nt][2] + bb[2], 0.f);
            float v3 = fmaxf(acc[mt][nt][3] + bb[3], 0.f);
            *(u16x4*)(t1buf + ((o >> 3) * 64 + nn) * 8 + (o & 7)) =
                pack4(v0, v1, v2, v3);
          }
        }
      }
    } else if (j > 0) {
      const int idx = cw * 64 + ln;   // 0..511
      if (idx < 128) {
        const int o3 = idx >> 6;
        const int n = idx & 63;
        float v = b3[o3];
#pragma unroll
        for (int w = 0; w < 8; w++) v += pbuf[w][o3][n];
        out[((b * 2 + o3) * 256 + p0 + (n >> 3)) * 256 + (qt0 + j - 1) * 8 + (n & 7)] = v;
      }
    }
    __syncthreads();
  }
}

// ---------------------------------------------------------------------------
extern "C" void kernel_launch(void* const* d_in, const int* in_sizes, int n_in,
                              void* d_out, int out_size, void* d_ws, size_t ws_size,
                              hipStream_t stream) {
  (void)in_sizes; (void)n_in; (void)out_size; (void)ws_size;
  const float* x          = (const float*)d_in[0];
  const int*   pidx       = (const int*)d_in[1];
  const int*   cidx       = (const int*)d_in[2];
  const float* pre_w      = (const float*)d_in[3];
  const float* pre_b      = (const float*)d_in[4];
  const float* post_w     = (const float*)d_in[5];
  const float* post_b     = (const float*)d_in[6];
  const float* post_out_w = (const float*)d_in[7];
  const float* post_out_b = (const float*)d_in[8];
  float* out = (float*)d_out;

  u16* ws   = (u16*)d_ws;
  u16* w1s  = ws;              // post_w[0] staged bf16: 65536 u16
  u16* w2s  = ws + 65536;      // post_w[1] staged bf16
  u16* flat = ws + 131072;     // node features bf16 [2048][256]
  // ws use: 655360 u16 = 1.31 MB

  dense_edge_k1<<<192, 256, 0, stream>>>(x, pre_w, pre_b, post_w, w1s, flat);
  dense_edge_main<<<256, 1024, 0, stream>>>(flat, pidx, cidx, w1s, w2s,
                                            post_b, post_b + 256,
                                            post_out_w, post_out_b, out);
}